// Round 13
// baseline (315.214 us; speedup 1.0000x reference)
//
#include <hip/hip_runtime.h>
#include <math.h>

#define S_LEN 2048
#define DH 64
#define BH_N 64
#define BQ 128
#define KT 64

typedef __attribute__((ext_vector_type(8))) short bf16x8;
typedef __attribute__((ext_vector_type(4))) float f32x4;
typedef __attribute__((ext_vector_type(4))) short s16x4;

__device__ __forceinline__ unsigned short f2bf(float f) {
  unsigned int u = __float_as_uint(f);
  u += 0x7fffu + ((u >> 16) & 1u);
  return (unsigned short)(u >> 16);
}

__device__ __forceinline__ unsigned cvt_pk(float lo, float hi) {
  unsigned r;
  asm("v_cvt_pk_bf16_f32 %0, %1, %2" : "=v"(r) : "v"(lo), "v"(hi));
  return r;
}

// R11 base (XCD swizzle + 2-tile groups + nt stores + burst-ordered epilogue).
// Change: QK^T operands SWAPPED -> mfma(K,Q) gives C[m=k][n=q]: lane owns
// q=lane&15 and 4 CONSECUTIVE k per reg quad. W stores become f32x4 nt
// (4x fewer instrs, same burst shape). ldsW CONTENT is unchanged ([q][k]
// bf16, same swizzle) -> PV/O path bit-identical to R11.
// (R12 fix: nt store must use ext_vector type, not HIP float4 struct.)
__global__ __launch_bounds__(256, 2)
void curve_attn_kernel(const float* __restrict__ Qg,
                       const float* __restrict__ Kg,
                       const float* __restrict__ Vg,
                       float* __restrict__ Og,
                       float* __restrict__ Wg,
                       float sc_l2e, float neg_l2C)
{
  __shared__ unsigned short ldsK[2][64 * 64];   // [tile][k_local][d], swizzled
  __shared__ unsigned short ldsV[2][64 * 64];   // [tile][d][k_local], swizzled
  __shared__ unsigned short ldsW[4][32 * 64];   // per-wave [q_local][k_local], swizzled

  const int tid  = threadIdx.x;
  const int lane = tid & 63;
  const int wv   = tid >> 6;
  const int lr   = lane & 15;
  const int lg   = lane >> 4;

  // XCD-aware swizzle (nwg = 1024, 8 XCDs, 128 blocks per XCD chunk)
  const int bid = (blockIdx.x & 7) * 128 + (blockIdx.x >> 3);
  const int bh  = bid >> 4;
  const int qt  = (bid & 15) * BQ;

  const size_t sd = (size_t)S_LEN * DH;
  const float* Qb = Qg + (size_t)bh * sd;
  const float* Kb = Kg + (size_t)bh * sd;
  const float* Vb = Vg + (size_t)bh * sd;
  float* Ob = Og + (size_t)bh * sd;
  float* Wb = Wg + (size_t)bh * (size_t)S_LEN * S_LEN;

  const int qrow0 = qt + wv * 32;

  // ---- Q fragments (R1 verbatim): lane holds q=lr, kdim=8*lg+i ----
  bf16x8 qf[2][2];
#pragma unroll
  for (int mb = 0; mb < 2; ++mb)
#pragma unroll
    for (int kb = 0; kb < 2; ++kb) {
      const float* src = Qb + (size_t)(qrow0 + mb * 16 + lr) * DH + kb * 32 + lg * 8;
      float4 a = *(const float4*)src;
      float4 b = *(const float4*)(src + 4);
      bf16x8 q;
      q[0] = (short)f2bf(a.x); q[1] = (short)f2bf(a.y);
      q[2] = (short)f2bf(a.z); q[3] = (short)f2bf(a.w);
      q[4] = (short)f2bf(b.x); q[5] = (short)f2bf(b.y);
      q[6] = (short)f2bf(b.z); q[7] = (short)f2bf(b.w);
      qf[mb][kb] = q;
    }

  f32x4 oacc[2][4];
#pragma unroll
  for (int i = 0; i < 2; ++i)
#pragma unroll
    for (int j = 0; j < 4; ++j)
      oacc[i][j] = (f32x4){0.f, 0.f, 0.f, 0.f};

  // staging thread mapping (R1 verbatim)
  const int kr = tid >> 2;          // K row 0..63
  const int kc = (tid & 3) * 4;     // K col base {0,4,8,12}
  const int vr = (tid >> 4) * 4;    // V k-row quad base
  const int vc = (tid & 15) * 4;    // V d-col quad base

  auto stage = [&](int t0, int buf) {
    // K tile
    {
      const float* src = Kb + (size_t)(t0 + kr) * DH + kc;
#pragma unroll
      for (int j = 0; j < 4; ++j) {
        float4 v = *(const float4*)(src + 16 * j);
        int e  = kr * 64 + kc + 16 * j;
        int se = e ^ ((kr & 7) << 3);
        s16x4 p;
        p[0] = (short)f2bf(v.x); p[1] = (short)f2bf(v.y);
        p[2] = (short)f2bf(v.z); p[3] = (short)f2bf(v.w);
        *(s16x4*)&ldsK[buf][se] = p;
      }
    }
    // V tile (transposed)
    {
      float4 vv[4];
      const float* src = Vb + (size_t)(t0 + vr) * DH + vc;
#pragma unroll
      for (int jr = 0; jr < 4; ++jr)
        vv[jr] = *(const float4*)(src + jr * DH);
#pragma unroll
      for (int jj = 0; jj < 4; ++jj) {
        int row = vc + jj;            // d index
        int e   = row * 64 + vr;      // col = k index
        int se  = e ^ ((row & 7) << 3);
        s16x4 p;
        p[0] = (short)f2bf(((const float*)&vv[0])[jj]);
        p[1] = (short)f2bf(((const float*)&vv[1])[jj]);
        p[2] = (short)f2bf(((const float*)&vv[2])[jj]);
        p[3] = (short)f2bf(((const float*)&vv[3])[jj]);
        *(s16x4*)&ldsV[buf][se] = p;
      }
    }
  };

  auto compute = [&](int buf, int kt) {
    // ---- swapped QK^T: mfma(K,Q) -> C[m=k][n=q]; lane=q, reg=k ----
    f32x4 sacc[2][4];
#pragma unroll
    for (int i = 0; i < 2; ++i)
#pragma unroll
      for (int j = 0; j < 4; ++j)
        sacc[i][j] = (f32x4){0.f, 0.f, 0.f, 0.f};

#pragma unroll
    for (int db = 0; db < 2; ++db) {
      bf16x8 kf[4];
#pragma unroll
      for (int nb = 0; nb < 4; ++nb) {
        int row = nb * 16 + lr;                   // k_idx
        int e   = (row * 64 + db * 32 + lg * 8) ^ ((row & 7) << 3);
        kf[nb] = *(const bf16x8*)&ldsK[buf][e];
      }
#pragma unroll
      for (int mb = 0; mb < 2; ++mb)
#pragma unroll
        for (int nb = 0; nb < 4; ++nb)
          sacc[mb][nb] = __builtin_amdgcn_mfma_f32_16x16x32_bf16(
              kf[nb], qf[mb][db], sacc[mb][nb], 0, 0, 0);
    }

    // ---- epilogue: lane owns q=lr, k=nb*16+lg*4+r -> f32x4 nt stores ----
#pragma unroll
    for (int mb = 0; mb < 2; ++mb) {
      int qrow = qrow0 + mb * 16 + lr;            // this lane's q row
      float* base = Wb + (size_t)qrow * S_LEN + kt + lg * 4;
#pragma unroll
      for (int nb = 0; nb < 4; ++nb) {
        float w0 = exp2f(sacc[mb][nb][0] * sc_l2e + neg_l2C);
        float w1 = exp2f(sacc[mb][nb][1] * sc_l2e + neg_l2C);
        float w2 = exp2f(sacc[mb][nb][2] * sc_l2e + neg_l2C);
        float w3 = exp2f(sacc[mb][nb][3] * sc_l2e + neg_l2C);
        f32x4 wq = {w0, w1, w2, w3};
        __builtin_nontemporal_store(wq, (f32x4*)(base + nb * 16));
        // ldsW: row q, 4 consecutive k -> uint2 (content identical to R11)
        int row = mb * 16 + lr;
        int e   = (row * 64 + nb * 16 + lg * 4) ^ ((row & 7) << 3);
        uint2 pp = {cvt_pk(w0, w1), cvt_pk(w2, w3)};
        *(uint2*)&ldsW[wv][e] = pp;
      }
    }

    // ---- PV (R11 verbatim): A=W, B=V -> C[m=q][n=d] ----
#pragma unroll
    for (int kb = 0; kb < 2; ++kb) {
      bf16x8 af[2];
#pragma unroll
      for (int mb = 0; mb < 2; ++mb) {
        int row = mb * 16 + lr;
        int e   = (row * 64 + kb * 32 + lg * 8) ^ ((row & 7) << 3);
        af[mb] = *(const bf16x8*)&ldsW[wv][e];
      }
#pragma unroll
      for (int db = 0; db < 4; ++db) {
        int row = db * 16 + lr;
        int e   = (row * 64 + kb * 32 + lg * 8) ^ ((row & 7) << 3);
        bf16x8 vf = *(const bf16x8*)&ldsV[buf][e];
#pragma unroll
        for (int mb = 0; mb < 2; ++mb)
          oacc[mb][db] = __builtin_amdgcn_mfma_f32_16x16x32_bf16(
              af[mb], vf, oacc[mb][db], 0, 0, 0);
      }
    }
  };

  // ---- main loop: 2 tiles per sync pair (R9-verbatim schedule) ----
#pragma unroll 1
  for (int kt = 0; kt < S_LEN; kt += 2 * KT) {
    __syncthreads();            // protect LDS from previous iteration's readers
    stage(kt, 0);
    stage(kt + KT, 1);
    __syncthreads();
    compute(0, kt);
    compute(1, kt + KT);
  }

  // ---- write O (nt, R11 verbatim) ----
#pragma unroll
  for (int mb = 0; mb < 2; ++mb)
#pragma unroll
    for (int db = 0; db < 4; ++db) {
      float* dst = Ob + (size_t)(qrow0 + mb * 16 + lg * 4) * DH + db * 16 + lr;
#pragma unroll
      for (int r = 0; r < 4; ++r)
        __builtin_nontemporal_store(oacc[mb][db][r], dst + (size_t)r * DH);
    }
}

extern "C" void kernel_launch(void* const* d_in, const int* in_sizes, int n_in,
                              void* d_out, int out_size, void* d_ws, size_t ws_size,
                              hipStream_t stream) {
  const float* Q = (const float*)d_in[0];
  const float* K = (const float*)d_in[1];
  const float* V = (const float*)d_in[2];
  float* O = (float*)d_out;
  float* W = O + (size_t)BH_N * S_LEN * DH;

  const double E = 2.718281828459045235360287;
  double C = 1.0 + exp(E);
  float neg_l2C = (float)(-(log(C) / log(2.0)));
  float sc_l2e  = (float)(0.125 / log(2.0));

  curve_attn_kernel<<<dim3(BH_N * (S_LEN / BQ)), dim3(256), 0, stream>>>(
      Q, K, V, O, W, sc_l2e, neg_l2C);
}